// Round 14
// baseline (95.966 us; speedup 1.0000x reference)
//
#include <hip/hip_runtime.h>
#include <hip/hip_bf16.h>

// Shapes
#define B_SZ   256
#define C_SZ   1024
#define HW     49
#define KDIM   50176        // C*H*W
#define DHID   768
#define NCLS   5

typedef __bf16 bf16x8 __attribute__((ext_vector_type(8)));
typedef __bf16 bf16x4 __attribute__((ext_vector_type(4)));
typedef float  f32x4  __attribute__((ext_vector_type(4)));

#define GLOAD_LDS16(gsrc, ldst) \
  __builtin_amdgcn_global_load_lds((__attribute__((address_space(1))) void*)(gsrc), \
                                   (__attribute__((address_space(3))) void*)(ldst), 16, 0, 0)

#define FENCE()   asm volatile("" ::: "memory")
#define BARRIER() do { \
    asm volatile("s_waitcnt lgkmcnt(0)" ::: "memory"); \
    __builtin_amdgcn_s_barrier(); \
    asm volatile("" ::: "memory"); \
  } while (0)

// ---------------------------------------------------------------------------
// Kernel A: per-(b,c) spatial max, pcam = feat*max -> bf16 (ws), copy feat -> out
// ---------------------------------------------------------------------------
__global__ __launch_bounds__(256) void pcam_kernel(const float* __restrict__ feat,
                                                   float* __restrict__ feat_out,
                                                   __bf16* __restrict__ pcam) {
  __shared__ float sv[1568];
  __shared__ float smax[32];
  const int tid = threadIdx.x;
  const size_t base = (size_t)blockIdx.x * 1568;

  const float4* src4 = (const float4*)(feat + base);
  float4* dst4 = (float4*)(feat_out + base);
  #pragma unroll
  for (int i = 0; i < 2; ++i) {
    int idx = tid + i * 256;
    if (idx < 392) {
      float4 v = src4[idx];
      dst4[idx] = v;
      ((float4*)sv)[idx] = v;
    }
  }
  __syncthreads();

  {
    const int r = tid >> 3, p = tid & 7;
    float mx = -INFINITY;
    for (int i = p; i < HW; i += 8) mx = fmaxf(mx, sv[r * HW + i]);
    #pragma unroll
    for (int off = 1; off < 8; off <<= 1) mx = fmaxf(mx, __shfl_xor(mx, off));
    if (p == 0) smax[r] = mx;
  }
  __syncthreads();

  for (int i = tid; i < 1568; i += 256) {
    int r = (i * 1338) >> 16;        // i/49 exact for i<1568
    float v = sv[i] * smax[r];
    pcam[base + i] = (__bf16)v;
  }
}

// ---------------------------------------------------------------------------
// Kernel B (v12 = R13-coalesced + BN=256 + counted vmcnt):
//   - BN=256 -> NT=3: A ingress halves (77MB), total 231MB; 96KB/step
//     amortizes per-step overhead 2x.
//   - counted vmcnt(8): per-iter order [B(s+2):8] COMPUTE vmcnt(8)
//     WRITE_B(s+1) BARRIER [A(s+2):4]. Oldest 12 = B(s+1)+A(s+1) complete;
//     B(s+2) rides through the whole compute phase. Taper: vmcnt(0) when
//     nothing newer in flight. Fences pin issue order (R5 sinking).
//   - B reg-staged COALESCED (instr = 4 rows x 256B contiguous), cvt in
//     regs, XOR-swizzled ds_write (R13). A via global_load_lds (R13).
//   - LDS 128KB (A 2x32 + B 2x32), 1 blk/CU; KSPLIT=85 -> 255 blocks.
// bf16 partials [ks][n][m]; reduce+relu downstream; no atomics.
// ---------------------------------------------------------------------------
#define BM 256
#define BN 256
#define BK 64
#define NT 3
#define KSPLIT 85
#define KSTEPS 784          // KDIM/BK

__global__ __launch_bounds__(512, 1) void gemm1_kernel(const __bf16* __restrict__ pcam,
                                                       const float* __restrict__ W1,
                                                       __bf16* __restrict__ h_part) {
  __shared__ __bf16 Asm[2][BM * BK];   // 2 x 32 KB
  __shared__ __bf16 Bsm[2][BN * BK];   // 2 x 32 KB

  const int tid  = threadIdx.x;
  const int lane = tid & 63;
  const int w    = tid >> 6;        // 0..7 : wave owns n-slab w*32..w*32+31
  const int c_   = lane & 15;
  const int q_   = lane >> 4;       // 0..3
  const int n0   = blockIdx.x * BN;
  const int ks   = blockIdx.y;
  const int s0   = (ks * KSTEPS) / KSPLIT;
  const int s1   = ((ks + 1) * KSTEPS) / KSPLIT;   // 9-10 steps

  // ---- A staging (global_load_lds): 2048 16B-units, 4/thread; source unit
  // pre-swizzled ^(m&7), linear LDS dest.
  unsigned a_off[4];
  #pragma unroll
  for (int it = 0; it < 4; ++it) {
    const unsigned ug = it * 512 + tid;
    const unsigned m  = ug >> 3;
    a_off[it] = m * (unsigned)KDIM + (((ug & 7) ^ (m & 7)) * 8u);
  }

  // ---- B staging (coalesced): instr i reads row n0+w*32+i*4+q_, 16B at
  // c_*16 within the row's 256B chunk -> 4 rows x 256B contiguous per instr.
  const float* bbase = W1 + (size_t)(n0 + w * 32 + q_) * KDIM + c_ * 4;
  // ds_write: row r, 8B-unit c_: phys16B=(c_>>1)^(r&7), half=c_&1.
  int bwr[8];
  #pragma unroll
  for (int i = 0; i < 8; ++i) {
    const int r = w * 32 + i * 4 + q_;
    bwr[i] = r * 128 + (((c_ >> 1) ^ (r & 7)) << 4) + ((c_ & 1) << 3);
  }

  f32x4 acc[16][2];
  #pragma unroll
  for (int i = 0; i < 16; ++i)
    #pragma unroll
    for (int j = 0; j < 2; ++j) acc[i][j] = f32x4{0.f, 0.f, 0.f, 0.f};

  // Two B reg sets (8 x f32x4 each), named statically (rule #20)
  f32x4 pA0, pA1, pA2, pA3, pA4, pA5, pA6, pA7;
  f32x4 pB0, pB1, pB2, pB3, pB4, pB5, pB6, pB7;

#define ISSUE_B8(Q0,Q1,Q2,Q3,Q4,Q5,Q6,Q7, s) do { \
    const size_t kb = (size_t)(s) * BK; \
    Q0 = *(const f32x4*)(bbase + kb + (size_t)( 0) * KDIM); \
    Q1 = *(const f32x4*)(bbase + kb + (size_t)( 4) * KDIM); \
    Q2 = *(const f32x4*)(bbase + kb + (size_t)( 8) * KDIM); \
    Q3 = *(const f32x4*)(bbase + kb + (size_t)(12) * KDIM); \
    Q4 = *(const f32x4*)(bbase + kb + (size_t)(16) * KDIM); \
    Q5 = *(const f32x4*)(bbase + kb + (size_t)(20) * KDIM); \
    Q6 = *(const f32x4*)(bbase + kb + (size_t)(24) * KDIM); \
    Q7 = *(const f32x4*)(bbase + kb + (size_t)(28) * KDIM); \
    FENCE(); \
  } while (0)

#define ISSUE_A(bi, s) do { \
    const unsigned ka = (unsigned)(s) * BK; \
    _Pragma("unroll") \
    for (int it = 0; it < 4; ++it) \
      GLOAD_LDS16(pcam + a_off[it] + ka, (char*)Asm[bi] + it * 8192 + w * 1024); \
    FENCE(); \
  } while (0)

#define WRITE_B8(bi, Q0,Q1,Q2,Q3,Q4,Q5,Q6,Q7) do { \
    _Pragma("unroll") \
    for (int i = 0; i < 8; ++i) { \
      const f32x4 v = (i==0)?Q0:(i==1)?Q1:(i==2)?Q2:(i==3)?Q3:(i==4)?Q4:(i==5)?Q5:(i==6)?Q6:Q7; \
      bf16x4 bv; \
      bv[0] = (__bf16)v[0]; bv[1] = (__bf16)v[1]; \
      bv[2] = (__bf16)v[2]; bv[3] = (__bf16)v[3]; \
      *(bf16x4*)((char*)Bsm[bi] + bwr[i]) = bv; \
    } \
  } while (0)

#define COMPUTE(bi) do { \
    _Pragma("unroll") \
    for (int ksub = 0; ksub < 2; ++ksub) { \
      const int u = ksub * 4 + q_; \
      bf16x8 bfr[2]; \
      _Pragma("unroll") \
      for (int j = 0; j < 2; ++j) { \
        const int rn = w * 32 + j * 16 + c_; \
        bfr[j] = *(const bf16x8*)((const char*)Bsm[bi] + rn * 128 + ((u ^ (rn & 7)) << 4)); \
      } \
      _Pragma("unroll") \
      for (int i = 0; i < 16; ++i) { \
        const int m = i * 16 + c_; \
        const bf16x8 af = *(const bf16x8*)((const char*)Asm[bi] + m * 128 + ((u ^ (m & 7)) << 4)); \
        acc[i][0] = __builtin_amdgcn_mfma_f32_16x16x32_bf16(af, bfr[0], acc[i][0], 0, 0, 0); \
        acc[i][1] = __builtin_amdgcn_mfma_f32_16x16x32_bf16(af, bfr[1], acc[i][1], 0, 0, 0); \
      } \
    } \
  } while (0)

  // ---- prologue: B(s0)->setA[8], A(s0)->buf0[4], B(s0+1)->setB[8]
  ISSUE_B8(pA0,pA1,pA2,pA3,pA4,pA5,pA6,pA7, s0);
  ISSUE_A(0, s0);
  if (s0 + 1 < s1) {
    ISSUE_B8(pB0,pB1,pB2,pB3,pB4,pB5,pB6,pB7, s0 + 1);
    asm volatile("s_waitcnt vmcnt(8)" ::: "memory");   // B(s0)+A(s0) done
  } else {
    asm volatile("s_waitcnt vmcnt(0)" ::: "memory");
  }
  WRITE_B8(0, pA0,pA1,pA2,pA3,pA4,pA5,pA6,pA7);
  BARRIER();
  if (s0 + 1 < s1) ISSUE_A(1, s0 + 1);

  // steady state invariant at iter s (cur=(s-s0)&1):
  //   LDS[cur] = A(s),B(s) ready; set[cur^1] = B(s+1) in flight/landed;
  //   A(s+1) DMA in flight into buf[cur^1].
  for (int s = s0; s < s1; ++s) {
    const int cur = (s - s0) & 1;
    if (s + 2 < s1) {
      if (cur == 0) ISSUE_B8(pA0,pA1,pA2,pA3,pA4,pA5,pA6,pA7, s + 2);
      else          ISSUE_B8(pB0,pB1,pB2,pB3,pB4,pB5,pB6,pB7, s + 2);
    }
    COMPUTE(cur);
    if (s + 1 < s1) {
      if (s + 2 < s1) asm volatile("s_waitcnt vmcnt(8)" ::: "memory");
      else            asm volatile("s_waitcnt vmcnt(0)" ::: "memory");
      if (cur == 0) WRITE_B8(1, pB0,pB1,pB2,pB3,pB4,pB5,pB6,pB7);
      else          WRITE_B8(0, pA0,pA1,pA2,pA3,pA4,pA5,pA6,pA7);
      BARRIER();
      if (s + 2 < s1) ISSUE_A(cur, s + 2);
    }
  }

  // ---- epilogue: bf16 partial slice [ks][n][m] (m fastest, 4 per lane)
  __bf16* out = h_part + (size_t)ks * DHID * B_SZ;
  #pragma unroll
  for (int j = 0; j < 2; ++j) {
    const int n = n0 + w * 32 + j * 16 + c_;
    #pragma unroll
    for (int i = 0; i < 16; ++i) {
      const int mb = i * 16 + q_ * 4;
      bf16x4 pv;
      pv[0] = (__bf16)acc[i][j][0]; pv[1] = (__bf16)acc[i][j][1];
      pv[2] = (__bf16)acc[i][j][2]; pv[3] = (__bf16)acc[i][j][3];
      *(bf16x4*)(out + (size_t)n * B_SZ + mb) = pv;
    }
  }
#undef ISSUE_B8
#undef ISSUE_A
#undef WRITE_B8
#undef COMPUTE
}

// ---------------------------------------------------------------------------
// Kernel C: reduce bf16 split-K partials, add b1, relu -> h[m][n] (fp32)
// ---------------------------------------------------------------------------
__global__ __launch_bounds__(256) void reduce_kernel(const __bf16* __restrict__ h_part,
                                                     const float* __restrict__ b1,
                                                     float* __restrict__ h) {
  const int n = blockIdx.x;
  const int m = threadIdx.x;
  float s = 0.f;
  #pragma unroll 5
  for (int ks = 0; ks < KSPLIT; ++ks)
    s += (float)h_part[((size_t)ks * DHID + n) * B_SZ + m];
  float v = s + b1[n];
  h[(size_t)m * DHID + n] = v > 0.f ? v : 0.f;
}

// ---------------------------------------------------------------------------
// Kernel D: logits = h @ W2^T + b2. One wave per batch row.
// ---------------------------------------------------------------------------
__global__ __launch_bounds__(64) void head_kernel(const float* __restrict__ h,
                                                  const float* __restrict__ W2,
                                                  const float* __restrict__ b2,
                                                  float* __restrict__ logits) {
  const int m = blockIdx.x;
  const int lane = threadIdx.x;
  float hv[12];
  #pragma unroll
  for (int j = 0; j < 12; ++j) hv[j] = h[(size_t)m * DHID + j * 64 + lane];
  #pragma unroll
  for (int c = 0; c < NCLS; ++c) {
    float s = 0.f;
    #pragma unroll
    for (int j = 0; j < 12; ++j) s += hv[j] * W2[c * DHID + j * 64 + lane];
    #pragma unroll
    for (int off = 32; off > 0; off >>= 1) s += __shfl_xor(s, off);
    if (lane == 0) logits[m * NCLS + c] = s + b2[c];
  }
}

// ---------------------------------------------------------------------------
extern "C" void kernel_launch(void* const* d_in, const int* in_sizes, int n_in,
                              void* d_out, int out_size, void* d_ws, size_t ws_size,
                              hipStream_t stream) {
  const float* feat = (const float*)d_in[0];
  const float* W1   = (const float*)d_in[1];
  const float* b1   = (const float*)d_in[2];
  const float* W2   = (const float*)d_in[3];
  const float* b2   = (const float*)d_in[4];

  float* logits   = (float*)d_out;
  float* feat_out = (float*)d_out + (size_t)B_SZ * NCLS;

  char* ws = (char*)d_ws;
  __bf16* pcam   = (__bf16*)ws;                                   // 25.7 MB
  __bf16* h_part = (__bf16*)(ws + (size_t)B_SZ * KDIM * 2);       // 85*768*256*2 = 33.4 MB
  float*  h      = (float*)(ws + (size_t)B_SZ * KDIM * 2
                               + (size_t)KSPLIT * DHID * B_SZ * 2); // 786 KB

  pcam_kernel<<<(B_SZ * C_SZ) / 32, 256, 0, stream>>>(feat, feat_out, pcam);
  gemm1_kernel<<<dim3(NT, KSPLIT), 512, 0, stream>>>(pcam, W1, h_part);
  reduce_kernel<<<DHID, 256, 0, stream>>>(h_part, b1, h);
  head_kernel<<<B_SZ, 64, 0, stream>>>(h, W2, b2, logits);
}